// Round 1
// baseline (223.341 us; speedup 1.0000x reference)
//
#include <hip/hip_runtime.h>
#include <cstddef>

// DCT-II matrix (float32 cast of numpy's float64 values)
static constexpr float D8[8][8] = {
  { 0.35355339059327373f, 0.35355339059327373f, 0.35355339059327373f, 0.35355339059327373f,
    0.35355339059327373f, 0.35355339059327373f, 0.35355339059327373f, 0.35355339059327373f},
  { 0.4903926402016152f,  0.4157348061512726f,  0.27778511650980114f, 0.09754516100806417f,
   -0.09754516100806417f,-0.27778511650980114f,-0.4157348061512726f, -0.4903926402016152f},
  { 0.46193976625564337f, 0.19134171618254492f,-0.19134171618254492f,-0.46193976625564337f,
   -0.46193976625564337f,-0.19134171618254492f, 0.19134171618254492f, 0.46193976625564337f},
  { 0.4157348061512726f, -0.09754516100806417f,-0.4903926402016152f, -0.27778511650980114f,
    0.27778511650980114f, 0.4903926402016152f,  0.09754516100806417f,-0.4157348061512726f},
  { 0.35355339059327373f,-0.35355339059327373f,-0.35355339059327373f, 0.35355339059327373f,
    0.35355339059327373f,-0.35355339059327373f,-0.35355339059327373f, 0.35355339059327373f},
  { 0.27778511650980114f,-0.4903926402016152f,  0.09754516100806417f, 0.4157348061512726f,
   -0.4157348061512726f, -0.09754516100806417f, 0.4903926402016152f, -0.27778511650980114f},
  { 0.19134171618254492f,-0.46193976625564337f, 0.46193976625564337f,-0.19134171618254492f,
   -0.19134171618254492f, 0.46193976625564337f,-0.46193976625564337f, 0.19134171618254492f},
  { 0.09754516100806417f,-0.27778511650980114f, 0.4157348061512726f, -0.4903926402016152f,
    0.4903926402016152f, -0.4157348061512726f,  0.27778511650980114f,-0.09754516100806417f},
};

// Quality-95 quant tables: q = clamp(floor((base*10+50)/100), 1, 255)
static constexpr float QLt[8][8] = {
  {2,1,1,2,2,4,5,6},
  {1,1,1,2,3,6,6,6},
  {1,1,2,2,4,6,7,6},
  {1,2,2,3,5,9,8,6},
  {2,2,4,6,7,11,10,8},
  {2,4,6,6,8,10,11,9},
  {5,6,8,9,10,12,12,10},
  {7,9,10,10,11,10,10,10},
};
static constexpr float QCt[8][8] = {
  {2,2,2,5,10,10,10,10},
  {2,2,3,7,10,10,10,10},
  {2,3,6,10,10,10,10,10},
  {5,7,10,10,10,10,10,10},
  {10,10,10,10,10,10,10,10},
  {10,10,10,10,10,10,10,10},
  {10,10,10,10,10,10,10,10},
  {10,10,10,10,10,10,10,10},
};

static constexpr float C255  = (float)(1.0/255.0);  // fl(1/255): matches jnp's f32 divisor
static constexpr float RC255 = 1.0f / C255;         // correctly-rounded reciprocal (constexpr IEEE)

// Markstein exactly-rounded division by a constant c with precomputed r = fl(1/c):
// result is bit-identical to IEEE x/c (round-to-nearest), but 3 VALU ops instead of
// the ~9-op v_div_scale/v_rcp/v_div_fixup sequence the compiler emits for '/'.
__device__ __forceinline__ float exact_div(float x, float c, float r) {
  float q0 = x * r;
  float e  = fmaf(-c, q0, x);
  return fmaf(e, r, q0);
}

// u[k] = sum_j D8[k][j] * x[j]   (contract with D's 2nd index)
__device__ __forceinline__ void dct8(const float x[8], float u[8]) {
  #pragma unroll
  for (int k = 0; k < 8; ++k) {
    float a = D8[k][0] * x[0];
    #pragma unroll
    for (int j = 1; j < 8; ++j) a += D8[k][j] * x[j];
    u[k] = a;
  }
}

// u[j] = sum_m x[m] * D8[m][j]   (contract with D's 1st index)
__device__ __forceinline__ void idct8(const float x[8], float u[8]) {
  #pragma unroll
  for (int j = 0; j < 8; ++j) {
    float a = x[0] * D8[0][j];
    #pragma unroll
    for (int m = 1; m < 8; ++m) a += x[m] * D8[m][j];
    u[j] = a;
  }
}

// In-register 8x8 transpose distributed one row per lane across an aligned
// 8-lane group (lane = t&7, groups contained in the wave). Each xor stage s
// swaps lane-bit-s with register-bit-s: element (L,r) with (L&s)!=(r&s) moves
// to (L^s, r^s). Verified trace: X[3][5]: s=1 stay, s=2 ->(1,7), s=4 ->(5,3). OK.
__device__ __forceinline__ void xpose8(float v[8], int lane) {
  #pragma unroll
  for (int s = 1; s < 8; s <<= 1) {
    const bool hi = (lane & s) != 0;
    #pragma unroll
    for (int r0 = 0; r0 < 8; ++r0) {
      if (r0 & s) continue;
      const int r1 = r0 | s;
      float send = hi ? v[r0] : v[r1];
      float got  = __shfl_xor(send, s, 64);
      if (hi) v[r0] = got; else v[r1] = got;
    }
  }
}

// Tile: 16 rows x 128 cols per block. Grid (W/128=4, H/16=32, B=32), 256 thr.
// LDS 13.8 KB (was 31.2 KB): S1/S2 transpose buffers replaced by shfl_xor
// butterflies -> 6 barriers reduced to 2, occupancy cap moves to 8 blocks/CU.
__global__ __launch_bounds__(256) void jpeg_rt(const float* __restrict__ in,
                                               float* __restrict__ out)
{
  // Row strides padded (132, 68) to keep b128 16B-aligned and bank aliasing
  // <= 2-way (free on gfx950, m136).
  __shared__ __align__(16) float Yp[16][132];
  __shared__ __align__(16) float Cbp[8][68];
  __shared__ __align__(16) float Crp[8][68];
  __shared__ __align__(16) float QTs[2][8][8];  // [plane][col l][row m] = Q[m][l]
  __shared__ __align__(16) float RQs[2][8][8];  // correctly-rounded 1/Q

  const int t   = threadIdx.x;
  const int tx  = blockIdx.x;   // 0..3
  const int ty  = blockIdx.y;   // 0..31
  const int img = blockIdx.z;   // 0..31

  const int pr = t >> 5;        // patch row 0..7   (pixel rows 2pr, 2pr+1)
  const int pc = t & 31;        // patch col 0..31  (pixel cols 4pc..4pc+3)

  // Quant tables transposed into LDS + exact reciprocals (one IEEE divide per
  // entry, once per block; runtime divide guarantees correctly-rounded 1/q).
  if (t < 128) {
    const int pl = t >> 6, i = (t >> 3) & 7, m = t & 7;
    const float q = pl ? QCt[m][i] : QLt[m][i];
    QTs[pl][i][m] = q;
    RQs[pl][i][m] = 1.0f / q;
  }

  // ---------------- stage 1: load 2x4 patch, color convert, plane writes
  {
    float yv[2][4];
    float cbv[2][4], crv[2][4];
    #pragma unroll
    for (int rr = 0; rr < 2; ++rr) {
      const size_t grow = (size_t)img * 512 + (size_t)(ty*16 + 2*pr + rr);
      const float* rp = in + (grow*512 + (size_t)(tx*128 + 4*pc))*3;
      float4 A = ((const float4*)rp)[0];
      float4 Bq = ((const float4*)rp)[1];
      float4 Cq = ((const float4*)rp)[2];
      float px[12] = {A.x,A.y,A.z,A.w,Bq.x,Bq.y,Bq.z,Bq.w,Cq.x,Cq.y,Cq.z,Cq.w};
      #pragma unroll
      for (int p = 0; p < 4; ++p) {
        float r = fminf(fmaxf(floorf(exact_div(px[3*p+0], C255, RC255)), 0.0f), 255.0f);
        float g = fminf(fmaxf(floorf(exact_div(px[3*p+1], C255, RC255)), 0.0f), 255.0f);
        float b = fminf(fmaxf(floorf(exact_div(px[3*p+2], C255, RC255)), 0.0f), 255.0f);
        float y  =  0.299f*r + 0.587f*g + 0.114f*b;
        float cb = -0.168736f*r - 0.331264f*g + 0.5f*b + 128.0f;
        float cr =  0.5f*r - 0.418688f*g - 0.081312f*b + 128.0f;
        yv[rr][p]  = y - 128.0f;
        cbv[rr][p] = cb;
        crv[rr][p] = cr;
      }
    }
    *(float4*)&Yp[2*pr+0][4*pc] = make_float4(yv[0][0],yv[0][1],yv[0][2],yv[0][3]);
    *(float4*)&Yp[2*pr+1][4*pc] = make_float4(yv[1][0],yv[1][1],yv[1][2],yv[1][3]);
    float cb0 = ((cbv[0][0]+cbv[0][1]) + (cbv[1][0]+cbv[1][1]))*0.25f - 128.0f;
    float cb1 = ((cbv[0][2]+cbv[0][3]) + (cbv[1][2]+cbv[1][3]))*0.25f - 128.0f;
    float cr0 = ((crv[0][0]+crv[0][1]) + (crv[1][0]+crv[1][1]))*0.25f - 128.0f;
    float cr1 = ((crv[0][2]+crv[0][3]) + (crv[1][2]+crv[1][3]))*0.25f - 128.0f;
    *(float2*)&Cbp[pr][2*pc] = make_float2(cb0, cb1);
    *(float2*)&Crp[pr][2*pc] = make_float2(cr0, cr1);
  }
  __syncthreads();

  // ---------------- luma: full DCT -> quant -> IDCT in registers.
  // Group g = 8 consecutive lanes owns one 8x8 block; lane l holds row l.
  // Each group reads/writes only its own Yp region and all its lanes are in
  // one wave (lockstep), so no barrier is needed around the in-place update.
  {
    const int g = t >> 3, l = t & 7;
    const int br = g >> 4, bc = g & 15;
    float* rowp = &Yp[br*8 + l][bc*8];
    float v[8], u[8];
    *(float4*)&v[0] = *(const float4*)&rowp[0];
    *(float4*)&v[4] = *(const float4*)&rowp[4];
    dct8(v, u);          // u = (X * D^T) row l
    xpose8(u, l);        // lane l now holds column l
    dct8(u, v);          // v[k] = coef[k][l]
    float qv[8], rv[8];
    *(float4*)&qv[0] = *(const float4*)&QTs[0][l][0];
    *(float4*)&qv[4] = *(const float4*)&QTs[0][l][4];
    *(float4*)&rv[0] = *(const float4*)&RQs[0][l][0];
    *(float4*)&rv[4] = *(const float4*)&RQs[0][l][4];
    #pragma unroll
    for (int m = 0; m < 8; ++m)
      v[m] = rintf(exact_div(v[m], qv[m], rv[m])) * qv[m];
    idct8(v, u);         // u = (D^T * deq) column l
    xpose8(u, l);        // lane l now holds row l
    idct8(u, v);         // v = rec row l
    *(float4*)&rowp[0] = *(float4*)&v[0];
    *(float4*)&rowp[4] = *(float4*)&v[4];
  }
  // ---------------- chroma: 16 blocks on threads 0..127 (same recipe)
  if (t < 128) {
    const int g = t >> 3, l = t & 7;          // g: 0..7 Cb, 8..15 Cr
    float* plane = (g & 8) ? &Crp[0][0] : &Cbp[0][0];
    float* rowp = plane + l*68 + (g & 7)*8;
    float v[8], u[8];
    *(float4*)&v[0] = *(const float4*)&rowp[0];
    *(float4*)&v[4] = *(const float4*)&rowp[4];
    dct8(v, u);
    xpose8(u, l);
    dct8(u, v);
    float qv[8], rv[8];
    *(float4*)&qv[0] = *(const float4*)&QTs[1][l][0];
    *(float4*)&qv[4] = *(const float4*)&QTs[1][l][4];
    *(float4*)&rv[0] = *(const float4*)&RQs[1][l][0];
    *(float4*)&rv[4] = *(const float4*)&RQs[1][l][4];
    #pragma unroll
    for (int m = 0; m < 8; ++m)
      v[m] = rintf(exact_div(v[m], qv[m], rv[m])) * qv[m];
    idct8(v, u);
    xpose8(u, l);
    idct8(u, v);
    *(float4*)&rowp[0] = *(float4*)&v[0];
    *(float4*)&rowp[4] = *(float4*)&v[4];
  }
  __syncthreads();

  // ---------------- output: upsample chroma, YCbCr->RGB, round/clip, /255
  {
    float y0[4], y1[4];
    *(float4*)y0 = *(const float4*)&Yp[2*pr+0][4*pc];
    *(float4*)y1 = *(const float4*)&Yp[2*pr+1][4*pc];
    float2 cbp2 = *(const float2*)&Cbp[pr][2*pc];
    float2 crp2 = *(const float2*)&Crp[pr][2*pc];
    float cbq[2] = {cbp2.x, cbp2.y};
    float crq[2] = {crp2.x, crp2.y};
    #pragma unroll
    for (int rr = 0; rr < 2; ++rr) {
      float ov[12];
      #pragma unroll
      for (int p = 0; p < 4; ++p) {
        float y2  = (rr ? y1[p] : y0[p]) + 128.0f;
        float cb2 = cbq[p>>1] + 128.0f;
        float cr2 = crq[p>>1] + 128.0f;
        float r2 = y2 + 1.402f*(cr2 - 128.0f);
        float g2 = y2 - 0.344136f*(cb2 - 128.0f) - 0.714136f*(cr2 - 128.0f);
        float b2 = y2 + 1.772f*(cb2 - 128.0f);
        ov[3*p+0] = exact_div(rintf(fminf(fmaxf(r2, 0.0f), 255.0f)), 255.0f, C255);
        ov[3*p+1] = exact_div(rintf(fminf(fmaxf(g2, 0.0f), 255.0f)), 255.0f, C255);
        ov[3*p+2] = exact_div(rintf(fminf(fmaxf(b2, 0.0f), 255.0f)), 255.0f, C255);
      }
      const size_t grow = (size_t)img * 512 + (size_t)(ty*16 + 2*pr + rr);
      float* op = out + (grow*512 + (size_t)(tx*128 + 4*pc))*3;
      ((float4*)op)[0] = make_float4(ov[0],ov[1],ov[2],ov[3]);
      ((float4*)op)[1] = make_float4(ov[4],ov[5],ov[6],ov[7]);
      ((float4*)op)[2] = make_float4(ov[8],ov[9],ov[10],ov[11]);
    }
  }
}

extern "C" void kernel_launch(void* const* d_in, const int* in_sizes, int n_in,
                              void* d_out, int out_size, void* d_ws, size_t ws_size,
                              hipStream_t stream) {
  (void)in_sizes; (void)n_in; (void)d_ws; (void)ws_size; (void)out_size;
  const float* x = (const float*)d_in[0];
  float* out = (float*)d_out;
  dim3 grid(4, 32, 32);   // W/128, H/16, B
  jpeg_rt<<<grid, dim3(256), 0, stream>>>(x, out);
}

// Round 2
// 182.448 us; speedup vs baseline: 1.2241x; 1.2241x over previous
//
#include <hip/hip_runtime.h>
#include <cstddef>

// DCT-II matrix (float32 cast of numpy's float64 values)
static constexpr float D8[8][8] = {
  { 0.35355339059327373f, 0.35355339059327373f, 0.35355339059327373f, 0.35355339059327373f,
    0.35355339059327373f, 0.35355339059327373f, 0.35355339059327373f, 0.35355339059327373f},
  { 0.4903926402016152f,  0.4157348061512726f,  0.27778511650980114f, 0.09754516100806417f,
   -0.09754516100806417f,-0.27778511650980114f,-0.4157348061512726f, -0.4903926402016152f},
  { 0.46193976625564337f, 0.19134171618254492f,-0.19134171618254492f,-0.46193976625564337f,
   -0.46193976625564337f,-0.19134171618254492f, 0.19134171618254492f, 0.46193976625564337f},
  { 0.4157348061512726f, -0.09754516100806417f,-0.4903926402016152f, -0.27778511650980114f,
    0.27778511650980114f, 0.4903926402016152f,  0.09754516100806417f,-0.4157348061512726f},
  { 0.35355339059327373f,-0.35355339059327373f,-0.35355339059327373f, 0.35355339059327373f,
    0.35355339059327373f,-0.35355339059327373f,-0.35355339059327373f, 0.35355339059327373f},
  { 0.27778511650980114f,-0.4903926402016152f,  0.09754516100806417f, 0.4157348061512726f,
   -0.4157348061512726f, -0.09754516100806417f, 0.4903926402016152f, -0.27778511650980114f},
  { 0.19134171618254492f,-0.46193976625564337f, 0.46193976625564337f,-0.19134171618254492f,
   -0.19134171618254492f, 0.46193976625564337f,-0.46193976625564337f, 0.19134171618254492f},
  { 0.09754516100806417f,-0.27778511650980114f, 0.4157348061512726f, -0.4903926402016152f,
    0.4903926402016152f, -0.4157348061512726f,  0.27778511650980114f,-0.09754516100806417f},
};

// Quality-95 quant tables: q = clamp(floor((base*10+50)/100), 1, 255)
static constexpr float QLt[8][8] = {
  {2,1,1,2,2,4,5,6},
  {1,1,1,2,3,6,6,6},
  {1,1,2,2,4,6,7,6},
  {1,2,2,3,5,9,8,6},
  {2,2,4,6,7,11,10,8},
  {2,4,6,6,8,10,11,9},
  {5,6,8,9,10,12,12,10},
  {7,9,10,10,11,10,10,10},
};
static constexpr float QCt[8][8] = {
  {2,2,2,5,10,10,10,10},
  {2,2,3,7,10,10,10,10},
  {2,3,6,10,10,10,10,10},
  {5,7,10,10,10,10,10,10},
  {10,10,10,10,10,10,10,10},
  {10,10,10,10,10,10,10,10},
  {10,10,10,10,10,10,10,10},
  {10,10,10,10,10,10,10,10},
};

static constexpr float C255  = (float)(1.0/255.0);  // fl(1/255): matches jnp's f32 divisor
static constexpr float RC255 = 1.0f / C255;         // correctly-rounded reciprocal (constexpr IEEE)

// Markstein exactly-rounded division by a constant c with precomputed r = fl(1/c):
// bit-identical to IEEE x/c (round-to-nearest), 3 VALU ops instead of the ~9-op
// v_div_scale/v_rcp/v_div_fixup sequence the compiler emits for '/'.
__device__ __forceinline__ float exact_div(float x, float c, float r) {
  float q0 = x * r;
  float e  = fmaf(-c, q0, x);
  return fmaf(e, r, q0);
}

// u[k] = sum_j D8[k][j] * x[j]   (contract with D's 2nd index)
__device__ __forceinline__ void dct8(const float x[8], float u[8]) {
  #pragma unroll
  for (int k = 0; k < 8; ++k) {
    float a = D8[k][0] * x[0];
    #pragma unroll
    for (int j = 1; j < 8; ++j) a += D8[k][j] * x[j];
    u[k] = a;
  }
}

// u[j] = sum_m x[m] * D8[m][j]   (contract with D's 1st index)
__device__ __forceinline__ void idct8(const float x[8], float u[8]) {
  #pragma unroll
  for (int j = 0; j < 8; ++j) {
    float a = x[0] * D8[0][j];
    #pragma unroll
    for (int m = 1; m < 8; ++m) a += x[m] * D8[m][j];
    u[j] = a;
  }
}

// In-register 8x8 transpose, one row per lane across an aligned 8-lane group.
// Stage s swaps lane-bit-s with register-bit-s. BRANCH-FREE: both elements of
// each register pair are written unconditionally via selects with compile-time
// indices — no divergent stores into the private array (round-1 post-mortem:
// `if (hi) v[r0]=...` defeated SROA, arrays went to scratch, +60MB WRITE_SIZE).
__device__ __forceinline__ void xpose8(float v[8], int lane) {
  #pragma unroll
  for (int s = 1; s < 8; s <<= 1) {
    const bool hi = (lane & s) != 0;
    #pragma unroll
    for (int r0 = 0; r0 < 8; ++r0) {
      if (r0 & s) continue;            // compile-time skip
      const int r1 = r0 | s;
      const float a = v[r0], b = v[r1];
      const float send = hi ? a : b;
      const float got  = __shfl_xor(send, s, 64);
      v[r0] = hi ? got : a;            // unconditional write, select value
      v[r1] = hi ? b   : got;          // unconditional write, select value
    }
  }
}

// Tile: 16 rows x 128 cols per block. Grid (W/128=4, H/16=32, B=32), 256 thr.
// LDS 13.8 KB: S1/S2 transpose buffers replaced by shfl_xor butterflies ->
// 6 barriers reduced to 2.
__global__ __launch_bounds__(256) void jpeg_rt(const float* __restrict__ in,
                                               float* __restrict__ out)
{
  // Row strides padded (132, 68) to keep b128 16B-aligned and bank aliasing
  // <= 2-way (free on gfx950, m136).
  __shared__ __align__(16) float Yp[16][132];
  __shared__ __align__(16) float Cbp[8][68];
  __shared__ __align__(16) float Crp[8][68];
  __shared__ __align__(16) float QTs[2][8][8];  // [plane][col l][row m] = Q[m][l]
  __shared__ __align__(16) float RQs[2][8][8];  // correctly-rounded 1/Q

  const int t   = threadIdx.x;
  const int tx  = blockIdx.x;   // 0..3
  const int ty  = blockIdx.y;   // 0..31
  const int img = blockIdx.z;   // 0..31

  const int pr = t >> 5;        // patch row 0..7   (pixel rows 2pr, 2pr+1)
  const int pc = t & 31;        // patch col 0..31  (pixel cols 4pc..4pc+3)

  // Quant tables transposed into LDS + exact reciprocals (one IEEE divide per
  // entry, once per block; runtime divide guarantees correctly-rounded 1/q).
  if (t < 128) {
    const int pl = t >> 6, i = (t >> 3) & 7, m = t & 7;
    const float q = pl ? QCt[m][i] : QLt[m][i];
    QTs[pl][i][m] = q;
    RQs[pl][i][m] = 1.0f / q;
  }

  // ---------------- stage 1: load 2x4 patch, color convert, plane writes
  {
    float yv[2][4];
    float cbv[2][4], crv[2][4];
    #pragma unroll
    for (int rr = 0; rr < 2; ++rr) {
      const size_t grow = (size_t)img * 512 + (size_t)(ty*16 + 2*pr + rr);
      const float* rp = in + (grow*512 + (size_t)(tx*128 + 4*pc))*3;
      float4 A = ((const float4*)rp)[0];
      float4 Bq = ((const float4*)rp)[1];
      float4 Cq = ((const float4*)rp)[2];
      float px[12] = {A.x,A.y,A.z,A.w,Bq.x,Bq.y,Bq.z,Bq.w,Cq.x,Cq.y,Cq.z,Cq.w};
      #pragma unroll
      for (int p = 0; p < 4; ++p) {
        float r = fminf(fmaxf(floorf(exact_div(px[3*p+0], C255, RC255)), 0.0f), 255.0f);
        float g = fminf(fmaxf(floorf(exact_div(px[3*p+1], C255, RC255)), 0.0f), 255.0f);
        float b = fminf(fmaxf(floorf(exact_div(px[3*p+2], C255, RC255)), 0.0f), 255.0f);
        float y  =  0.299f*r + 0.587f*g + 0.114f*b;
        float cb = -0.168736f*r - 0.331264f*g + 0.5f*b + 128.0f;
        float cr =  0.5f*r - 0.418688f*g - 0.081312f*b + 128.0f;
        yv[rr][p]  = y - 128.0f;
        cbv[rr][p] = cb;
        crv[rr][p] = cr;
      }
    }
    *(float4*)&Yp[2*pr+0][4*pc] = make_float4(yv[0][0],yv[0][1],yv[0][2],yv[0][3]);
    *(float4*)&Yp[2*pr+1][4*pc] = make_float4(yv[1][0],yv[1][1],yv[1][2],yv[1][3]);
    float cb0 = ((cbv[0][0]+cbv[0][1]) + (cbv[1][0]+cbv[1][1]))*0.25f - 128.0f;
    float cb1 = ((cbv[0][2]+cbv[0][3]) + (cbv[1][2]+cbv[1][3]))*0.25f - 128.0f;
    float cr0 = ((crv[0][0]+crv[0][1]) + (crv[1][0]+crv[1][1]))*0.25f - 128.0f;
    float cr1 = ((crv[0][2]+crv[0][3]) + (crv[1][2]+crv[1][3]))*0.25f - 128.0f;
    *(float2*)&Cbp[pr][2*pc] = make_float2(cb0, cb1);
    *(float2*)&Crp[pr][2*pc] = make_float2(cr0, cr1);
  }
  __syncthreads();

  // ---------------- luma: full DCT -> quant -> IDCT in registers.
  // Group g = 8 consecutive lanes owns one 8x8 block; lane l holds row l.
  // Groups are wave-contained (lockstep) and touch disjoint Yp regions, so no
  // barrier is needed around the in-place update.
  {
    const int g = t >> 3, l = t & 7;
    const int br = g >> 4, bc = g & 15;
    float* rowp = &Yp[br*8 + l][bc*8];
    // Load via float4 temps; never take the address of a private array.
    float4 L0 = *(const float4*)&rowp[0];
    float4 L1 = *(const float4*)&rowp[4];
    float v[8] = {L0.x, L0.y, L0.z, L0.w, L1.x, L1.y, L1.z, L1.w};
    float u[8];
    dct8(v, u);          // u = (X * D^T) row l
    xpose8(u, l);        // lane l now holds column l
    dct8(u, v);          // v[k] = coef[k][l]
    float4 Q0 = *(const float4*)&QTs[0][l][0];
    float4 Q1 = *(const float4*)&QTs[0][l][4];
    float4 R0 = *(const float4*)&RQs[0][l][0];
    float4 R1 = *(const float4*)&RQs[0][l][4];
    float qv[8] = {Q0.x,Q0.y,Q0.z,Q0.w,Q1.x,Q1.y,Q1.z,Q1.w};
    float rv[8] = {R0.x,R0.y,R0.z,R0.w,R1.x,R1.y,R1.z,R1.w};
    #pragma unroll
    for (int m = 0; m < 8; ++m)
      v[m] = rintf(exact_div(v[m], qv[m], rv[m])) * qv[m];
    idct8(v, u);         // u = (D^T * deq) column l
    xpose8(u, l);        // lane l now holds row l
    idct8(u, v);         // v = rec row l
    *(float4*)&rowp[0] = make_float4(v[0],v[1],v[2],v[3]);
    *(float4*)&rowp[4] = make_float4(v[4],v[5],v[6],v[7]);
  }
  // ---------------- chroma: 16 blocks on threads 0..127 (same recipe)
  if (t < 128) {
    const int g = t >> 3, l = t & 7;          // g: 0..7 Cb, 8..15 Cr
    float* plane = (g & 8) ? &Crp[0][0] : &Cbp[0][0];
    float* rowp = plane + l*68 + (g & 7)*8;
    float4 L0 = *(const float4*)&rowp[0];
    float4 L1 = *(const float4*)&rowp[4];
    float v[8] = {L0.x, L0.y, L0.z, L0.w, L1.x, L1.y, L1.z, L1.w};
    float u[8];
    dct8(v, u);
    xpose8(u, l);
    dct8(u, v);
    float4 Q0 = *(const float4*)&QTs[1][l][0];
    float4 Q1 = *(const float4*)&QTs[1][l][4];
    float4 R0 = *(const float4*)&RQs[1][l][0];
    float4 R1 = *(const float4*)&RQs[1][l][4];
    float qv[8] = {Q0.x,Q0.y,Q0.z,Q0.w,Q1.x,Q1.y,Q1.z,Q1.w};
    float rv[8] = {R0.x,R0.y,R0.z,R0.w,R1.x,R1.y,R1.z,R1.w};
    #pragma unroll
    for (int m = 0; m < 8; ++m)
      v[m] = rintf(exact_div(v[m], qv[m], rv[m])) * qv[m];
    idct8(v, u);
    xpose8(u, l);
    idct8(u, v);
    *(float4*)&rowp[0] = make_float4(v[0],v[1],v[2],v[3]);
    *(float4*)&rowp[4] = make_float4(v[4],v[5],v[6],v[7]);
  }
  __syncthreads();

  // ---------------- output: upsample chroma, YCbCr->RGB, round/clip, /255
  {
    float4 Y0 = *(const float4*)&Yp[2*pr+0][4*pc];
    float4 Y1 = *(const float4*)&Yp[2*pr+1][4*pc];
    float y0[4] = {Y0.x, Y0.y, Y0.z, Y0.w};
    float y1[4] = {Y1.x, Y1.y, Y1.z, Y1.w};
    float2 cbp2 = *(const float2*)&Cbp[pr][2*pc];
    float2 crp2 = *(const float2*)&Crp[pr][2*pc];
    float cbq[2] = {cbp2.x, cbp2.y};
    float crq[2] = {crp2.x, crp2.y};
    #pragma unroll
    for (int rr = 0; rr < 2; ++rr) {
      float ov[12];
      #pragma unroll
      for (int p = 0; p < 4; ++p) {
        float y2  = (rr ? y1[p] : y0[p]) + 128.0f;
        float cb2 = cbq[p>>1] + 128.0f;
        float cr2 = crq[p>>1] + 128.0f;
        float r2 = y2 + 1.402f*(cr2 - 128.0f);
        float g2 = y2 - 0.344136f*(cb2 - 128.0f) - 0.714136f*(cr2 - 128.0f);
        float b2 = y2 + 1.772f*(cb2 - 128.0f);
        ov[3*p+0] = exact_div(rintf(fminf(fmaxf(r2, 0.0f), 255.0f)), 255.0f, C255);
        ov[3*p+1] = exact_div(rintf(fminf(fmaxf(g2, 0.0f), 255.0f)), 255.0f, C255);
        ov[3*p+2] = exact_div(rintf(fminf(fmaxf(b2, 0.0f), 255.0f)), 255.0f, C255);
      }
      const size_t grow = (size_t)img * 512 + (size_t)(ty*16 + 2*pr + rr);
      float* op = out + (grow*512 + (size_t)(tx*128 + 4*pc))*3;
      ((float4*)op)[0] = make_float4(ov[0],ov[1],ov[2],ov[3]);
      ((float4*)op)[1] = make_float4(ov[4],ov[5],ov[6],ov[7]);
      ((float4*)op)[2] = make_float4(ov[8],ov[9],ov[10],ov[11]);
    }
  }
}

extern "C" void kernel_launch(void* const* d_in, const int* in_sizes, int n_in,
                              void* d_out, int out_size, void* d_ws, size_t ws_size,
                              hipStream_t stream) {
  (void)in_sizes; (void)n_in; (void)d_ws; (void)ws_size; (void)out_size;
  const float* x = (const float*)d_in[0];
  float* out = (float*)d_out;
  dim3 grid(4, 32, 32);   // W/128, H/16, B
  jpeg_rt<<<grid, dim3(256), 0, stream>>>(x, out);
}